// Round 1
// baseline (757.609 us; speedup 1.0000x reference)
//
#include <hip/hip_runtime.h>

// ---------------------------------------------------------------------------
// LinearShift: out = round_to_fixed(x) @ (exp2(shift)*(1-2*sign))^T + round_to_fixed(bias)
// M=8192, K=4096 (IN_F), N=4096 (OUT_F). All inputs f32, output f32.
//
// Strategy: x_q is a multiple of 2^-8 with |x_q|<8 -> EXACT in fp16.
// weight is +-2^s -> exact in fp16 (tail s<-24 flushes to 0, contribution <1e-7).
// So: convert x->fp16 (quantized), (shift,sign)->fp16 weight, then f16 MFMA GEMM
// with fp32 accumulation (m97 128^2-tile structure, global_load_lds width 16).
// ---------------------------------------------------------------------------

typedef _Float16 half8 __attribute__((ext_vector_type(8)));
typedef _Float16 half4v __attribute__((ext_vector_type(4)));
typedef float floatx4 __attribute__((ext_vector_type(4)));

#define DEVINL static __device__ __forceinline__

// round_to_fixed, bits=16: delta=2^-8, bound=2^15
DEVINL float round_to_fixed(float x) {
    float r = floorf(fmaf(x, 256.0f, 0.5f));   // x*256 exact (pow2), single round on +0.5
    r = fminf(fmaxf(r, -32768.0f), 32767.0f);
    return r * 0.00390625f;                    // * 2^-8
}

// ---- kernel 1: quantize x (f32) -> fp16, 4 elems/thread, grid-stride ------
__global__ __launch_bounds__(256) void quant_x_kernel(const float* __restrict__ x,
                                                      _Float16* __restrict__ xh,
                                                      int n4) {
    const float4* __restrict__ xv = (const float4*)x;
    half4v* __restrict__ ov = (half4v*)xh;
    const int stride = gridDim.x * blockDim.x;
    for (int i = blockIdx.x * blockDim.x + threadIdx.x; i < n4; i += stride) {
        float4 v = xv[i];
        half4v h;
        h[0] = (_Float16)round_to_fixed(v.x);
        h[1] = (_Float16)round_to_fixed(v.y);
        h[2] = (_Float16)round_to_fixed(v.z);
        h[3] = (_Float16)round_to_fixed(v.w);
        ov[i] = h;
    }
}

// ---- kernel 2: weight = (1-2*sign) * 2^round(shift) -> fp16 ----------------
__global__ __launch_bounds__(256) void make_w_kernel(const float* __restrict__ shift,
                                                     const float* __restrict__ sign,
                                                     _Float16* __restrict__ wh,
                                                     int n4) {
    const float4* __restrict__ sv = (const float4*)shift;
    const float4* __restrict__ gv = (const float4*)sign;
    half4v* __restrict__ ov = (half4v*)wh;
    const int stride = gridDim.x * blockDim.x;
    for (int i = blockIdx.x * blockDim.x + threadIdx.x; i < n4; i += stride) {
        float4 s = sv[i];
        float4 g = gv[i];
        half4v h;
        h[0] = (_Float16)ldexpf(1.0f - 2.0f * g.x, (int)rintf(s.x));
        h[1] = (_Float16)ldexpf(1.0f - 2.0f * g.y, (int)rintf(s.y));
        h[2] = (_Float16)ldexpf(1.0f - 2.0f * g.z, (int)rintf(s.z));
        h[3] = (_Float16)ldexpf(1.0f - 2.0f * g.w, (int)rintf(s.w));
        ov[i] = h;
    }
}

// ---- kernel 3: GEMM C[M,N] = A[M,K](f16) * Bw[N,K](f16)^T + bias_q ---------
// m97 structure: 128x128 tile, BK=32, 4 waves (2x2), 16 MFMA 16x16x32/wave/step,
// global_load_lds width 16, single LDS buffer, 2 barriers per K-step.
#define BM 128
#define BN 128
#define BK 32

__global__ __launch_bounds__(256) void gemm_f16_kernel(const _Float16* __restrict__ A,
                                                       const _Float16* __restrict__ Bw,
                                                       const float* __restrict__ bias,
                                                       float* __restrict__ C,
                                                       int M, int N, int K) {
    __shared__ _Float16 sA[BM * BK];   // 8 KiB
    __shared__ _Float16 sB[BN * BK];   // 8 KiB

    const int tid  = threadIdx.x;
    const int lane = tid & 63;
    const int wave = tid >> 6;
    const int wm = wave >> 1;          // 0..1
    const int wn = wave & 1;           // 0..1
    const int la = lane & 15;          // fragment row/col within 16
    const int lk = lane >> 4;          // 0..3: k-subgroup

    const int ntile_n = N / BN;        // 32
    const int bid = blockIdx.x;
    const int tm = (bid / ntile_n) * BM;
    const int tn = (bid % ntile_n) * BN;

    // staging: tile = 8 KiB = 8 chunks of 1 KiB (16 rows); each wave stages 2 chunks/operand.
    // lane i of a wave-load: row = chunk*16 + i/4, bytes (i&3)*16 within the 64B row.
    const int c0   = wave * 2;
    const int r0   = lane >> 2;        // 0..15
    const int koff = (lane & 3) * 8;   // f16 elems (8 per 16B)

    const _Float16* gA0 = A  + (size_t)(tm + c0 * 16      + r0) * K + koff;
    const _Float16* gA1 = A  + (size_t)(tm + c0 * 16 + 16 + r0) * K + koff;
    const _Float16* gB0 = Bw + (size_t)(tn + c0 * 16      + r0) * K + koff;
    const _Float16* gB1 = Bw + (size_t)(tn + c0 * 16 + 16 + r0) * K + koff;

    _Float16* lA0 = sA + c0 * 512;           // wave-uniform LDS dest (HW adds lane*16B)
    _Float16* lA1 = sA + c0 * 512 + 512;
    _Float16* lB0 = sB + c0 * 512;
    _Float16* lB1 = sB + c0 * 512 + 512;

    floatx4 acc[4][4];
#pragma unroll
    for (int m = 0; m < 4; ++m)
#pragma unroll
        for (int n = 0; n < 4; ++n)
            acc[m][n] = (floatx4)0.0f;

    const _Float16* pa = sA + (wm * 64 + la) * BK + lk * 8;
    const _Float16* pb = sB + (wn * 64 + la) * BK + lk * 8;

    const int NK = K / BK;
    for (int kt = 0; kt < NK; ++kt) {
        const size_t go = (size_t)kt * BK;
        __builtin_amdgcn_global_load_lds(
            (const __attribute__((address_space(1))) void*)(gA0 + go),
            (__attribute__((address_space(3))) void*)lA0, 16, 0, 0);
        __builtin_amdgcn_global_load_lds(
            (const __attribute__((address_space(1))) void*)(gA1 + go),
            (__attribute__((address_space(3))) void*)lA1, 16, 0, 0);
        __builtin_amdgcn_global_load_lds(
            (const __attribute__((address_space(1))) void*)(gB0 + go),
            (__attribute__((address_space(3))) void*)lB0, 16, 0, 0);
        __builtin_amdgcn_global_load_lds(
            (const __attribute__((address_space(1))) void*)(gB1 + go),
            (__attribute__((address_space(3))) void*)lB1, 16, 0, 0);
        __syncthreads();   // compiler drains vmcnt before s_barrier -> staging visible

        half8 af[4], bf[4];
#pragma unroll
        for (int m = 0; m < 4; ++m)
            af[m] = *(const half8*)(pa + m * 16 * BK);
#pragma unroll
        for (int n = 0; n < 4; ++n)
            bf[n] = *(const half8*)(pb + n * 16 * BK);

#pragma unroll
        for (int m = 0; m < 4; ++m)
#pragma unroll
            for (int n = 0; n < 4; ++n)
                acc[m][n] = __builtin_amdgcn_mfma_f32_16x16x32_f16(af[m], bf[n], acc[m][n], 0, 0, 0);

        __syncthreads();   // WAR: everyone done reading LDS before next stage
    }

    // epilogue: C/D layout (verified m89/m91): col = lane&15, row = (lane>>4)*4 + reg
    const int prow = tm + wm * 64 + lk * 4;
    const int pcol = tn + wn * 64 + la;
#pragma unroll
    for (int n = 0; n < 4; ++n) {
        const int col = pcol + n * 16;
        const float bq = round_to_fixed(bias[col]);
#pragma unroll
        for (int m = 0; m < 4; ++m) {
            const int row = prow + m * 16;
            float* cp = C + (size_t)row * N + col;
            floatx4 v = acc[m][n];
#pragma unroll
            for (int r = 0; r < 4; ++r)
                cp[(size_t)r * N] = v[r] + bq;
        }
    }
}

// ---------------------------------------------------------------------------
extern "C" void kernel_launch(void* const* d_in, const int* in_sizes, int n_in,
                              void* d_out, int out_size, void* d_ws, size_t ws_size,
                              hipStream_t stream) {
    const float* x     = (const float*)d_in[0];
    const float* shift = (const float*)d_in[1];
    const float* sign  = (const float*)d_in[2];
    const float* bias  = (const float*)d_in[3];
    float* out = (float*)d_out;

    const int M = 8192, K = 4096, N = 4096;

    _Float16* xh = (_Float16*)d_ws;                 // M*K f16 = 64 MiB
    _Float16* wh = xh + (size_t)M * K;              // N*K f16 = 32 MiB

    quant_x_kernel<<<2048, 256, 0, stream>>>(x, xh, M * K / 4);
    make_w_kernel<<<2048, 256, 0, stream>>>(shift, sign, wh, N * K / 4);
    gemm_f16_kernel<<<(M / BM) * (N / BN), 256, 0, stream>>>(xh, wh, bias, out, M, N, K);
}

// Round 3
// 654.908 us; speedup vs baseline: 1.1568x; 1.1568x over previous
//
#include <hip/hip_runtime.h>

// ---------------------------------------------------------------------------
// LinearShift: out = round_to_fixed(x) @ (exp2(shift)*(1-2*sign))^T + round_to_fixed(bias)
// M=8192, K=4096, N=4096. f32 in/out. x_q exact in fp16 (multiple of 2^-8, |x|<8);
// weight = +-2^s exact in fp16 down to s>=-24 (tail contributes <1e-7).
//
// Round 2 (resubmit after broker timeout): 256x256 8-phase GEMM template
// (T3+T4 counted vmcnt + T5 setprio), LINEAR LDS (st_16x32 swizzle deferred
// one round), XCD-swizzled grid, bit-constructed f16 weights, 16B stores.
// ---------------------------------------------------------------------------

typedef _Float16 half8 __attribute__((ext_vector_type(8)));
typedef float floatx4 __attribute__((ext_vector_type(4)));
typedef unsigned short ushort8 __attribute__((ext_vector_type(8)));

#define DEVINL static __device__ __forceinline__

// round_to_fixed, bits=16: delta=2^-8, bound=2^15
DEVINL float round_to_fixed(float x) {
    float r = floorf(fmaf(x, 256.0f, 0.5f));
    r = fminf(fmaxf(r, -32768.0f), 32767.0f);
    return r * 0.00390625f;
}

// ---- kernel 1: quantize x (f32) -> fp16, 8 elems/thread ---------------------
__global__ __launch_bounds__(256) void quant_x_kernel(const float* __restrict__ x,
                                                      _Float16* __restrict__ xh, int n8) {
    const int stride = gridDim.x * blockDim.x;
    for (int i = blockIdx.x * blockDim.x + threadIdx.x; i < n8; i += stride) {
        const float4* p = (const float4*)(x + (size_t)i * 8);
        float4 v0 = p[0], v1 = p[1];
        half8 h;
        h[0] = (_Float16)round_to_fixed(v0.x);
        h[1] = (_Float16)round_to_fixed(v0.y);
        h[2] = (_Float16)round_to_fixed(v0.z);
        h[3] = (_Float16)round_to_fixed(v0.w);
        h[4] = (_Float16)round_to_fixed(v1.x);
        h[5] = (_Float16)round_to_fixed(v1.y);
        h[6] = (_Float16)round_to_fixed(v1.z);
        h[7] = (_Float16)round_to_fixed(v1.w);
        *(half8*)(xh + (size_t)i * 8) = h;
    }
}

// ---- kernel 2: weight = (1-2*sign) * 2^round(shift) -> fp16 bits directly ---
DEVINL unsigned short w_bits(float s, float g) {
    int e16 = (int)rintf(s) + 15;                 // f16 biased exponent; s <= -6 so e16 <= 9
    unsigned short mag;
    if (e16 >= 1)        mag = (unsigned short)(e16 << 10);        // normal
    else if (e16 >= -9)  mag = (unsigned short)(1 << (e16 + 9));   // subnormal 2^(e16-15)
    else                 mag = 0;                                  // underflow -> 0
    return mag | (g >= 0.5f ? 0x8000u : 0u);
}

__global__ __launch_bounds__(256) void make_w_kernel(const float* __restrict__ shift,
                                                     const float* __restrict__ sign,
                                                     _Float16* __restrict__ wh, int n8) {
    const int stride = gridDim.x * blockDim.x;
    for (int i = blockIdx.x * blockDim.x + threadIdx.x; i < n8; i += stride) {
        const float4* sp = (const float4*)(shift + (size_t)i * 8);
        const float4* gp = (const float4*)(sign + (size_t)i * 8);
        float4 s0 = sp[0], s1 = sp[1];
        float4 g0 = gp[0], g1 = gp[1];
        ushort8 h;
        h[0] = w_bits(s0.x, g0.x);
        h[1] = w_bits(s0.y, g0.y);
        h[2] = w_bits(s0.z, g0.z);
        h[3] = w_bits(s0.w, g0.w);
        h[4] = w_bits(s1.x, g1.x);
        h[5] = w_bits(s1.y, g1.y);
        h[6] = w_bits(s1.z, g1.z);
        h[7] = w_bits(s1.w, g1.w);
        *(ushort8*)(wh + (size_t)i * 8) = h;
    }
}

// ---- kernel 3: 256x256 8-phase GEMM ----------------------------------------
// C[M,N] = A[M,K](f16) * Bw[N,K](f16)^T + bias_q. 512 threads = 8 waves (2M x 4N).
// LDS: double-buffered A[256][64] + B[256][64] f16 = 128 KiB. Linear layout.
// Half-tile order per K-tile: h0=Bh0(rows0-127) h1=Bh1 h2=Ah0 h3=Ah1.
// Stage stream H[s], s = 4*tile+h; phase j issues H[j+6] (6-ahead stagger).
// Per-tile phases: P1{rd aLo+b0; MFMA m0-3 n0-1} P2{rd b1; MFMA m0-3 n2-3}
//                  P3{rd aHi; MFMA m4-7 n2-3}    P4{vmcnt(4); MFMA m4-7 n0-1}
// Safety: t+2 B-halves staged at P3/P4 overwrite regions last read at P2
// (ordered by P2's end barrier); single counted vmcnt(4) per tile keeps 2
// half-tiles (4 loads) in flight across barriers.
#define BM 256
#define BN 256
#define BK 64

__global__ __launch_bounds__(512, 2) void gemm_f16_kernel(const _Float16* __restrict__ A,
                                                          const _Float16* __restrict__ Bw,
                                                          const float* __restrict__ bias,
                                                          float* __restrict__ C) {
    constexpr int M = 8192, N = 4096, K = 4096;
    constexpr int NT = K / BK;        // 64 K-tiles
    constexpr int NTN = N / BN;       // 16 tile-cols
    constexpr int NWG = (M / BM) * NTN;  // 512

    __shared__ _Float16 sA[2][BM * BK];   // 64 KiB
    __shared__ _Float16 sB[2][BN * BK];   // 64 KiB

    const int tid  = threadIdx.x;
    const int lane = tid & 63;
    const int wave = tid >> 6;        // 0..7
    const int wm = wave >> 2;         // 0..1 (M half)
    const int wn = wave & 3;          // 0..3 (N quarter)
    const int la = lane & 15;
    const int lk = lane >> 4;

    // XCD-aware swizzle (NWG=512, %8==0)
    const int bid0 = blockIdx.x;
    const int bid = (bid0 & 7) * (NWG / 8) + (bid0 >> 3);
    const int tm = (bid / NTN) * BM;
    const int tn = (bid % NTN) * BN;

    // staging geometry: per wave, per instr j in {0,1}: 64 lanes x 16B = 8 rows.
    // lane l -> row (l>>3), col f16 (l&7)*8; LDS dest linear = lane*16B. [m104]
    const int srow = wave * 16 + (lane >> 3);
    const int scol = (lane & 7) * 8;
    const _Float16* gA = A  + (size_t)(tm + srow) * K + scol;
    const _Float16* gB = Bw + (size_t)(tn + srow) * K + scol;
    const int lbase = wave * 16 * BK;     // wave-uniform LDS base (f16 units)

    auto STAGE = [&](int s) {
        if (s >= 4 * NT) return;
        const int t = s >> 2;
        const int h = s & 3;              // 0=Bh0 1=Bh1 2=Ah0 3=Ah1 (const-folded per call site)
        const int bufi = t & 1;
        const int k0 = t * BK;
        const int rh = (h & 1) * 128;
        const bool isA = (h >= 2);
        const _Float16* src = (isA ? gA : gB) + (size_t)rh * K + k0;
        _Float16* dst = (isA ? &sA[bufi][0] : &sB[bufi][0]) + rh * BK + lbase;
        __builtin_amdgcn_global_load_lds(
            (const __attribute__((address_space(1))) void*)src,
            (__attribute__((address_space(3))) void*)dst, 16, 0, 0);
        __builtin_amdgcn_global_load_lds(
            (const __attribute__((address_space(1))) void*)(src + (size_t)8 * K),
            (__attribute__((address_space(3))) void*)(dst + 8 * BK), 16, 0, 0);
    };

    floatx4 acc[8][4];
#pragma unroll
    for (int m = 0; m < 8; ++m)
#pragma unroll
        for (int n = 0; n < 4; ++n)
            acc[m][n] = (floatx4)0.0f;

    const int aOff = (wm * 128 + la) * BK + lk * 8;
    const int bOff = (wn * 64  + la) * BK + lk * 8;

    // prologue: tile0 all 4 halves + tile1 Bh0,Bh1 -> 12 loads/wave; keep 2 halves in flight
    STAGE(0); STAGE(1); STAGE(2); STAGE(3); STAGE(4); STAGE(5);
    asm volatile("s_waitcnt vmcnt(4)" ::: "memory");
    __builtin_amdgcn_s_barrier();

    for (int t = 0; t < NT; ++t) {
        const int bufi = t & 1;
        const _Float16* bufA = &sA[bufi][0];
        const _Float16* bufB = &sB[bufi][0];
        half8 aF[4][2], bF0[2][2], bF1[2][2];

        // ---------------- P1: read aLo + b0; stage t+1.Ah0; MFMA m0-3 n0-1 ---
#pragma unroll
        for (int m = 0; m < 4; ++m)
#pragma unroll
            for (int kk = 0; kk < 2; ++kk)
                aF[m][kk] = *(const half8*)(bufA + aOff + m * 16 * BK + kk * 32);
#pragma unroll
        for (int n = 0; n < 2; ++n)
#pragma unroll
            for (int kk = 0; kk < 2; ++kk)
                bF0[n][kk] = *(const half8*)(bufB + bOff + n * 16 * BK + kk * 32);
        STAGE(4 * t + 6);
        __builtin_amdgcn_s_barrier();
        asm volatile("s_waitcnt lgkmcnt(0)" ::: "memory");
        __builtin_amdgcn_sched_barrier(0);
        __builtin_amdgcn_s_setprio(1);
#pragma unroll
        for (int kk = 0; kk < 2; ++kk)
#pragma unroll
            for (int m = 0; m < 4; ++m)
#pragma unroll
                for (int n = 0; n < 2; ++n)
                    acc[m][n] = __builtin_amdgcn_mfma_f32_16x16x32_f16(aF[m][kk], bF0[n][kk], acc[m][n], 0, 0, 0);
        __builtin_amdgcn_s_setprio(0);
        __builtin_amdgcn_sched_barrier(0);
        __builtin_amdgcn_s_barrier();

        // ---------------- P2: read b1; stage t+1.Ah1; MFMA m0-3 n2-3 ---------
#pragma unroll
        for (int n = 0; n < 2; ++n)
#pragma unroll
            for (int kk = 0; kk < 2; ++kk)
                bF1[n][kk] = *(const half8*)(bufB + bOff + (n + 2) * 16 * BK + kk * 32);
        STAGE(4 * t + 7);
        __builtin_amdgcn_s_barrier();
        asm volatile("s_waitcnt lgkmcnt(0)" ::: "memory");
        __builtin_amdgcn_sched_barrier(0);
        __builtin_amdgcn_s_setprio(1);
#pragma unroll
        for (int kk = 0; kk < 2; ++kk)
#pragma unroll
            for (int m = 0; m < 4; ++m)
#pragma unroll
                for (int n = 0; n < 2; ++n)
                    acc[m][n + 2] = __builtin_amdgcn_mfma_f32_16x16x32_f16(aF[m][kk], bF1[n][kk], acc[m][n + 2], 0, 0, 0);
        __builtin_amdgcn_s_setprio(0);
        __builtin_amdgcn_sched_barrier(0);
        __builtin_amdgcn_s_barrier();

        // ---------------- P3: read aHi; stage t+2.Bh0; MFMA m4-7 n2-3 --------
#pragma unroll
        for (int m = 0; m < 4; ++m)
#pragma unroll
            for (int kk = 0; kk < 2; ++kk)
                aF[m][kk] = *(const half8*)(bufA + aOff + (m + 4) * 16 * BK + kk * 32);
        STAGE(4 * t + 8);
        __builtin_amdgcn_s_barrier();
        asm volatile("s_waitcnt lgkmcnt(0)" ::: "memory");
        __builtin_amdgcn_sched_barrier(0);
        __builtin_amdgcn_s_setprio(1);
#pragma unroll
        for (int kk = 0; kk < 2; ++kk)
#pragma unroll
            for (int m = 0; m < 4; ++m)
#pragma unroll
                for (int n = 0; n < 2; ++n)
                    acc[m + 4][n + 2] = __builtin_amdgcn_mfma_f32_16x16x32_f16(aF[m][kk], bF1[n][kk], acc[m + 4][n + 2], 0, 0, 0);
        __builtin_amdgcn_s_setprio(0);
        __builtin_amdgcn_sched_barrier(0);
        __builtin_amdgcn_s_barrier();

        // ---------------- P4: stage t+2.Bh1; counted vmcnt; MFMA m4-7 n0-1 ---
        STAGE(4 * t + 9);
        if (t < NT - 2) {
            asm volatile("s_waitcnt vmcnt(4)" ::: "memory");
        } else {
            asm volatile("s_waitcnt vmcnt(0)" ::: "memory");
        }
        __builtin_amdgcn_s_barrier();
        __builtin_amdgcn_sched_barrier(0);
        __builtin_amdgcn_s_setprio(1);
#pragma unroll
        for (int kk = 0; kk < 2; ++kk)
#pragma unroll
            for (int m = 0; m < 4; ++m)
#pragma unroll
                for (int n = 0; n < 2; ++n)
                    acc[m + 4][n] = __builtin_amdgcn_mfma_f32_16x16x32_f16(aF[m][kk], bF0[n][kk], acc[m + 4][n], 0, 0, 0);
        __builtin_amdgcn_s_setprio(0);
        __builtin_amdgcn_sched_barrier(0);
        __builtin_amdgcn_s_barrier();
    }

    // epilogue: C/D layout col=la (+n*16), row=lk*4+reg (+m*16) [m89/m91]
    float bq[4];
#pragma unroll
    for (int n = 0; n < 4; ++n)
        bq[n] = round_to_fixed(bias[tn + wn * 64 + n * 16 + la]);
#pragma unroll
    for (int m = 0; m < 8; ++m) {
        const int row0 = tm + wm * 128 + m * 16 + lk * 4;
#pragma unroll
        for (int n = 0; n < 4; ++n) {
            const int col = tn + wn * 64 + n * 16 + la;
            float* cp = C + (size_t)row0 * N + col;
            floatx4 v = acc[m][n];
#pragma unroll
            for (int r = 0; r < 4; ++r)
                cp[(size_t)r * N] = v[r] + bq[n];
        }
    }
}

// ---------------------------------------------------------------------------
extern "C" void kernel_launch(void* const* d_in, const int* in_sizes, int n_in,
                              void* d_out, int out_size, void* d_ws, size_t ws_size,
                              hipStream_t stream) {
    const float* x     = (const float*)d_in[0];
    const float* shift = (const float*)d_in[1];
    const float* sign  = (const float*)d_in[2];
    const float* bias  = (const float*)d_in[3];
    float* out = (float*)d_out;

    const int M = 8192, K = 4096, N = 4096;

    _Float16* xh = (_Float16*)d_ws;                 // M*K f16 = 64 MiB
    _Float16* wh = xh + (size_t)M * K;              // N*K f16 = 32 MiB

    quant_x_kernel<<<2048, 256, 0, stream>>>(x, xh, M * K / 8);
    make_w_kernel<<<2048, 256, 0, stream>>>(shift, sign, wh, N * K / 8);
    gemm_f16_kernel<<<(M / BM) * (N / BN), 512, 0, stream>>>(xh, wh, bias, out);
}

// Round 4
// 578.205 us; speedup vs baseline: 1.3103x; 1.1327x over previous
//
#include <hip/hip_runtime.h>

// ---------------------------------------------------------------------------
// LinearShift: out = round_to_fixed(x) @ (exp2(shift)*(1-2*sign))^T + round_to_fixed(bias)
// M=8192, K=4096, N=4096. f32 in/out. x_q exact in fp16 (multiple of 2^-8, |x|<8);
// weight = +-2^s exact in fp16 down to s>=-24 (tail contributes <1e-7).
//
// Round 4: + T2 LDS XOR-swizzle (both-sides: inverse-swizzled global source for
// global_load_lds linear dest + swizzled ds_read slot). Attacks the measured
// 7.55e7 SQ_LDS_BANK_CONFLICT (~32% of CU-cycles) from 16-way conflicts on
// 128B-row fragment reads. GEMM structure (8-phase, counted vmcnt, setprio)
// unchanged from round 3. Elementwise kernels unchanged (attribution).
// ---------------------------------------------------------------------------

typedef _Float16 half8 __attribute__((ext_vector_type(8)));
typedef float floatx4 __attribute__((ext_vector_type(4)));
typedef unsigned short ushort8 __attribute__((ext_vector_type(8)));

#define DEVINL static __device__ __forceinline__

// round_to_fixed, bits=16: delta=2^-8, bound=2^15
DEVINL float round_to_fixed(float x) {
    float r = floorf(fmaf(x, 256.0f, 0.5f));
    r = fminf(fmaxf(r, -32768.0f), 32767.0f);
    return r * 0.00390625f;
}

// ---- kernel 1: quantize x (f32) -> fp16, 8 elems/thread ---------------------
__global__ __launch_bounds__(256) void quant_x_kernel(const float* __restrict__ x,
                                                      _Float16* __restrict__ xh, int n8) {
    const int stride = gridDim.x * blockDim.x;
    for (int i = blockIdx.x * blockDim.x + threadIdx.x; i < n8; i += stride) {
        const float4* p = (const float4*)(x + (size_t)i * 8);
        float4 v0 = p[0], v1 = p[1];
        half8 h;
        h[0] = (_Float16)round_to_fixed(v0.x);
        h[1] = (_Float16)round_to_fixed(v0.y);
        h[2] = (_Float16)round_to_fixed(v0.z);
        h[3] = (_Float16)round_to_fixed(v0.w);
        h[4] = (_Float16)round_to_fixed(v1.x);
        h[5] = (_Float16)round_to_fixed(v1.y);
        h[6] = (_Float16)round_to_fixed(v1.z);
        h[7] = (_Float16)round_to_fixed(v1.w);
        *(half8*)(xh + (size_t)i * 8) = h;
    }
}

// ---- kernel 2: weight = (1-2*sign) * 2^round(shift) -> fp16 bits directly ---
DEVINL unsigned short w_bits(float s, float g) {
    int e16 = (int)rintf(s) + 15;                 // f16 biased exponent; s <= -6 so e16 <= 9
    unsigned short mag;
    if (e16 >= 1)        mag = (unsigned short)(e16 << 10);        // normal
    else if (e16 >= -9)  mag = (unsigned short)(1 << (e16 + 9));   // subnormal 2^(e16-15)
    else                 mag = 0;                                  // underflow -> 0
    return mag | (g >= 0.5f ? 0x8000u : 0u);
}

__global__ __launch_bounds__(256) void make_w_kernel(const float* __restrict__ shift,
                                                     const float* __restrict__ sign,
                                                     _Float16* __restrict__ wh, int n8) {
    const int stride = gridDim.x * blockDim.x;
    for (int i = blockIdx.x * blockDim.x + threadIdx.x; i < n8; i += stride) {
        const float4* sp = (const float4*)(shift + (size_t)i * 8);
        const float4* gp = (const float4*)(sign + (size_t)i * 8);
        float4 s0 = sp[0], s1 = sp[1];
        float4 g0 = gp[0], g1 = gp[1];
        ushort8 h;
        h[0] = w_bits(s0.x, g0.x);
        h[1] = w_bits(s0.y, g0.y);
        h[2] = w_bits(s0.z, g0.z);
        h[3] = w_bits(s0.w, g0.w);
        h[4] = w_bits(s1.x, g1.x);
        h[5] = w_bits(s1.y, g1.y);
        h[6] = w_bits(s1.z, g1.z);
        h[7] = w_bits(s1.w, g1.w);
        *(ushort8*)(wh + (size_t)i * 8) = h;
    }
}

// ---- kernel 3: 256x256 8-phase GEMM with T2 swizzle -------------------------
// C[M,N] = A[M,K](f16) * Bw[N,K](f16)^T + bias_q. 512 threads = 8 waves (2M x 4N).
// LDS: double-buffered A[256][64] + B[256][64] f16 = 128 KiB.
//
// T2 swizzle (rule #21 both-sides involution):
//   LDS[row][chunk j] holds GLOBAL[row][chunk j ^ (row&7)]   (chunk = 8 f16 = 16B)
//   - write side: gload_lds dest stays LINEAR (lane*16B); the SOURCE column for
//     lane l is chunk (l&7)^(l>>3)  (row = l>>3 mod 8; valid for both 8-row
//     halves since they differ by 8 == 0 mod 8).
//   - read side: fragment slot (lk+4kk) is read at LDS chunk (lk+4kk)^(la&7).
//   Result: 16-lane fragment groups spread over 8 slots (2 lanes/slot = free);
//   wave-balanced at the LDS BW floor.
#define BM 256
#define BN 256
#define BK 64

__global__ __launch_bounds__(512, 2) void gemm_f16_kernel(const _Float16* __restrict__ A,
                                                          const _Float16* __restrict__ Bw,
                                                          const float* __restrict__ bias,
                                                          float* __restrict__ C) {
    constexpr int M = 8192, N = 4096, K = 4096;
    constexpr int NT = K / BK;        // 64 K-tiles
    constexpr int NTN = N / BN;       // 16 tile-cols
    constexpr int NWG = (M / BM) * NTN;  // 512

    __shared__ _Float16 sA[2][BM * BK];   // 64 KiB
    __shared__ _Float16 sB[2][BN * BK];   // 64 KiB

    const int tid  = threadIdx.x;
    const int lane = tid & 63;
    const int wave = tid >> 6;        // 0..7
    const int wm = wave >> 2;         // 0..1 (M half)
    const int wn = wave & 3;          // 0..3 (N quarter)
    const int la = lane & 15;
    const int lk = lane >> 4;

    // XCD-aware swizzle (NWG=512, %8==0)
    const int bid0 = blockIdx.x;
    const int bid = (bid0 & 7) * (NWG / 8) + (bid0 >> 3);
    const int tm = (bid / NTN) * BM;
    const int tn = (bid % NTN) * BN;

    // staging geometry: per wave, per instr: 64 lanes x 16B = 8 rows x 128B.
    // lane l -> row (l>>3); SOURCE col chunk = (l&7)^(l>>3)  [T2 inverse swizzle];
    // LDS dest linear = wave base + lane*16B. [m104]
    const int srow = wave * 16 + (lane >> 3);
    const int scol = (((lane & 7) ^ (lane >> 3))) * 8;   // f16 units
    const _Float16* gA = A  + (size_t)(tm + srow) * K + scol;
    const _Float16* gB = Bw + (size_t)(tn + srow) * K + scol;
    const int lbase = wave * 16 * BK;     // wave-uniform LDS base (f16 units)

    auto STAGE = [&](int s) {
        if (s >= 4 * NT) return;
        const int t = s >> 2;
        const int h = s & 3;              // 0=Bh0 1=Bh1 2=Ah0 3=Ah1
        const int bufi = t & 1;
        const int k0 = t * BK;
        const int rh = (h & 1) * 128;
        const bool isA = (h >= 2);
        const _Float16* src = (isA ? gA : gB) + (size_t)rh * K + k0;
        _Float16* dst = (isA ? &sA[bufi][0] : &sB[bufi][0]) + rh * BK + lbase;
        __builtin_amdgcn_global_load_lds(
            (const __attribute__((address_space(1))) void*)src,
            (__attribute__((address_space(3))) void*)dst, 16, 0, 0);
        __builtin_amdgcn_global_load_lds(
            (const __attribute__((address_space(1))) void*)(src + (size_t)8 * K),
            (__attribute__((address_space(3))) void*)(dst + 8 * BK), 16, 0, 0);
    };

    floatx4 acc[8][4];
#pragma unroll
    for (int m = 0; m < 8; ++m)
#pragma unroll
        for (int n = 0; n < 4; ++n)
            acc[m][n] = (floatx4)0.0f;

    // fragment read bases: row part only; col chunk applied per-read with swizzle
    const int sw = la & 7;                        // row&7 for all fragment rows
    const int aRow = (wm * 128 + la) * BK;
    const int bRow = (wn * 64  + la) * BK;
    // swizzled col offsets (f16 units) for kk=0,1 at this lane's lk:
    const int c0 = ((lk    ) ^ sw) << 3;          // slot lk+0  -> LDS chunk
    const int c1 = ((lk + 4) ^ sw) << 3;          // slot lk+4  -> LDS chunk

    // prologue: tile0 all 4 halves + tile1 Bh0,Bh1; keep 2 half-tiles in flight
    STAGE(0); STAGE(1); STAGE(2); STAGE(3); STAGE(4); STAGE(5);
    asm volatile("s_waitcnt vmcnt(4)" ::: "memory");
    __builtin_amdgcn_s_barrier();

    for (int t = 0; t < NT; ++t) {
        const int bufi = t & 1;
        const _Float16* bufA = &sA[bufi][0];
        const _Float16* bufB = &sB[bufi][0];
        half8 aF[4][2], bF0[2][2], bF1[2][2];

        // ---------------- P1: read aLo + b0; stage t+1.Ah0; MFMA m0-3 n0-1 ---
#pragma unroll
        for (int m = 0; m < 4; ++m) {
            aF[m][0] = *(const half8*)(bufA + aRow + m * 16 * BK + c0);
            aF[m][1] = *(const half8*)(bufA + aRow + m * 16 * BK + c1);
        }
#pragma unroll
        for (int n = 0; n < 2; ++n) {
            bF0[n][0] = *(const half8*)(bufB + bRow + n * 16 * BK + c0);
            bF0[n][1] = *(const half8*)(bufB + bRow + n * 16 * BK + c1);
        }
        STAGE(4 * t + 6);
        __builtin_amdgcn_s_barrier();
        asm volatile("s_waitcnt lgkmcnt(0)" ::: "memory");
        __builtin_amdgcn_sched_barrier(0);
        __builtin_amdgcn_s_setprio(1);
#pragma unroll
        for (int kk = 0; kk < 2; ++kk)
#pragma unroll
            for (int m = 0; m < 4; ++m)
#pragma unroll
                for (int n = 0; n < 2; ++n)
                    acc[m][n] = __builtin_amdgcn_mfma_f32_16x16x32_f16(aF[m][kk], bF0[n][kk], acc[m][n], 0, 0, 0);
        __builtin_amdgcn_s_setprio(0);
        __builtin_amdgcn_sched_barrier(0);
        __builtin_amdgcn_s_barrier();

        // ---------------- P2: read b1; stage t+1.Ah1; MFMA m0-3 n2-3 ---------
#pragma unroll
        for (int n = 0; n < 2; ++n) {
            bF1[n][0] = *(const half8*)(bufB + bRow + (n + 2) * 16 * BK + c0);
            bF1[n][1] = *(const half8*)(bufB + bRow + (n + 2) * 16 * BK + c1);
        }
        STAGE(4 * t + 7);
        __builtin_amdgcn_s_barrier();
        asm volatile("s_waitcnt lgkmcnt(0)" ::: "memory");
        __builtin_amdgcn_sched_barrier(0);
        __builtin_amdgcn_s_setprio(1);
#pragma unroll
        for (int kk = 0; kk < 2; ++kk)
#pragma unroll
            for (int m = 0; m < 4; ++m)
#pragma unroll
                for (int n = 0; n < 2; ++n)
                    acc[m][n + 2] = __builtin_amdgcn_mfma_f32_16x16x32_f16(aF[m][kk], bF1[n][kk], acc[m][n + 2], 0, 0, 0);
        __builtin_amdgcn_s_setprio(0);
        __builtin_amdgcn_sched_barrier(0);
        __builtin_amdgcn_s_barrier();

        // ---------------- P3: read aHi; stage t+2.Bh0; MFMA m4-7 n2-3 --------
#pragma unroll
        for (int m = 0; m < 4; ++m) {
            aF[m][0] = *(const half8*)(bufA + aRow + (m + 4) * 16 * BK + c0);
            aF[m][1] = *(const half8*)(bufA + aRow + (m + 4) * 16 * BK + c1);
        }
        STAGE(4 * t + 8);
        __builtin_amdgcn_s_barrier();
        asm volatile("s_waitcnt lgkmcnt(0)" ::: "memory");
        __builtin_amdgcn_sched_barrier(0);
        __builtin_amdgcn_s_setprio(1);
#pragma unroll
        for (int kk = 0; kk < 2; ++kk)
#pragma unroll
            for (int m = 0; m < 4; ++m)
#pragma unroll
                for (int n = 0; n < 2; ++n)
                    acc[m + 4][n + 2] = __builtin_amdgcn_mfma_f32_16x16x32_f16(aF[m][kk], bF1[n][kk], acc[m + 4][n + 2], 0, 0, 0);
        __builtin_amdgcn_s_setprio(0);
        __builtin_amdgcn_sched_barrier(0);
        __builtin_amdgcn_s_barrier();

        // ---------------- P4: stage t+2.Bh1; counted vmcnt; MFMA m4-7 n0-1 ---
        STAGE(4 * t + 9);
        if (t < NT - 2) {
            asm volatile("s_waitcnt vmcnt(4)" ::: "memory");
        } else {
            asm volatile("s_waitcnt vmcnt(0)" ::: "memory");
        }
        __builtin_amdgcn_s_barrier();
        __builtin_amdgcn_sched_barrier(0);
        __builtin_amdgcn_s_setprio(1);
#pragma unroll
        for (int kk = 0; kk < 2; ++kk)
#pragma unroll
            for (int m = 0; m < 4; ++m)
#pragma unroll
                for (int n = 0; n < 2; ++n)
                    acc[m + 4][n] = __builtin_amdgcn_mfma_f32_16x16x32_f16(aF[m][kk], bF0[n][kk], acc[m + 4][n], 0, 0, 0);
        __builtin_amdgcn_s_setprio(0);
        __builtin_amdgcn_sched_barrier(0);
        __builtin_amdgcn_s_barrier();
    }

    // epilogue: C/D layout col=la (+n*16), row=lk*4+reg (+m*16) [m89/m91]
    float bq[4];
#pragma unroll
    for (int n = 0; n < 4; ++n)
        bq[n] = round_to_fixed(bias[tn + wn * 64 + n * 16 + la]);
#pragma unroll
    for (int m = 0; m < 8; ++m) {
        const int row0 = tm + wm * 128 + m * 16 + lk * 4;
#pragma unroll
        for (int n = 0; n < 4; ++n) {
            const int col = tn + wn * 64 + n * 16 + la;
            float* cp = C + (size_t)row0 * N + col;
            floatx4 v = acc[m][n];
#pragma unroll
            for (int r = 0; r < 4; ++r)
                cp[(size_t)r * N] = v[r] + bq[n];
        }
    }
}

// ---------------------------------------------------------------------------
extern "C" void kernel_launch(void* const* d_in, const int* in_sizes, int n_in,
                              void* d_out, int out_size, void* d_ws, size_t ws_size,
                              hipStream_t stream) {
    const float* x     = (const float*)d_in[0];
    const float* shift = (const float*)d_in[1];
    const float* sign  = (const float*)d_in[2];
    const float* bias  = (const float*)d_in[3];
    float* out = (float*)d_out;

    const int M = 8192, K = 4096, N = 4096;

    _Float16* xh = (_Float16*)d_ws;                 // M*K f16 = 64 MiB
    _Float16* wh = xh + (size_t)M * K;              // N*K f16 = 32 MiB

    quant_x_kernel<<<2048, 256, 0, stream>>>(x, xh, M * K / 8);
    make_w_kernel<<<2048, 256, 0, stream>>>(shift, sign, wh, N * K / 8);
    gemm_f16_kernel<<<(M / BM) * (N / BN), 512, 0, stream>>>(xh, wh, bias, out);
}